// Round 5
// baseline (337.654 us; speedup 1.0000x reference)
//
#include <hip/hip_runtime.h>
#include <hip/hip_bf16.h>
#include <stdint.h>

#define Ss   1024
#define MEMm 1024
#define Tt   2048
#define Dd   1024
#define Hh   16
#define DKk  64

typedef unsigned short u16;
using f32x4 = __attribute__((ext_vector_type(4))) float;
using s16x8 = __attribute__((ext_vector_type(8))) short;

__device__ __forceinline__ u16 f2bf(float x) {
  __hip_bfloat16 h = __float2bfloat16(x);
  return *(reinterpret_cast<u16*>(&h));
}
__device__ __forceinline__ float b2f(short s) {
  union { uint32_t u; float f; } c; c.u = ((uint32_t)(u16)s) << 16; return c.f;
}
__device__ __forceinline__ uint32_t pk2(float lo, float hi) {
  return (uint32_t)f2bf(lo) | ((uint32_t)f2bf(hi) << 16);
}
__device__ __forceinline__ f32x4 mfma16(s16x8 a, s16x8 b, f32x4 c) {
  return __builtin_amdgcn_mfma_f32_16x16x32_bf16(a, b, c, 0, 0, 0);
}
__device__ __forceinline__ void gl_lds16(const u16* g, u16* l) {
  __builtin_amdgcn_global_load_lds(
      (const __attribute__((address_space(1))) uint32_t*)g,
      (__attribute__((address_space(3))) uint32_t*)l, 16, 0, 0);
}
// 16-lane (fr-group) max via DPP butterfly: xor masks {1,2,7,15}
__device__ __forceinline__ float rowmax16(float x) {
  int v = __builtin_bit_cast(int, x);
  int t = __builtin_amdgcn_update_dpp(v, v, 0xB1, 0xF, 0xF, true);   // quad_perm [1,0,3,2] = ^1
  x = fmaxf(x, __builtin_bit_cast(float, t)); v = __builtin_bit_cast(int, x);
  t = __builtin_amdgcn_update_dpp(v, v, 0x4E, 0xF, 0xF, true);       // quad_perm [2,3,0,1] = ^2
  x = fmaxf(x, __builtin_bit_cast(float, t)); v = __builtin_bit_cast(int, x);
  t = __builtin_amdgcn_update_dpp(v, v, 0x141, 0xF, 0xF, true);      // row_half_mirror = ^7
  x = fmaxf(x, __builtin_bit_cast(float, t)); v = __builtin_bit_cast(int, x);
  t = __builtin_amdgcn_update_dpp(v, v, 0x140, 0xF, 0xF, true);      // row_mirror = ^15
  x = fmaxf(x, __builtin_bit_cast(float, t));
  return x;
}

// ---------------------------------------------------------------------------
// fp32 -> bf16 converts
// ---------------------------------------------------------------------------
__global__ __launch_bounds__(256)
void cvt_f32_bf16(const float* __restrict__ in, u16* __restrict__ out, int n8) {
  int i = blockIdx.x * 256 + threadIdx.x;
  const int stride = gridDim.x * 256;
  for (; i < n8; i += stride) {
    const float4* p = (const float4*)(in + (size_t)i * 8);
    const float4 a = p[0], bq = p[1];
    uint4 o;
    o.x = pk2(a.x, a.y);   o.y = pk2(a.z, a.w);
    o.z = pk2(bq.x, bq.y); o.w = pk2(bq.z, bq.w);
    *(uint4*)(out + (size_t)i * 8) = o;
  }
}
__global__ __launch_bounds__(256)
void cvt5(const float* __restrict__ w0, const float* __restrict__ w1,
          const float* __restrict__ w2, const float* __restrict__ w3,
          const float* __restrict__ w4, u16* __restrict__ dst) {
  const float* s;
  switch (blockIdx.y) {
    case 0: s = w0; break; case 1: s = w1; break; case 2: s = w2; break;
    case 3: s = w3; break; default: s = w4; break;
  }
  const int idx = blockIdx.x * 256 + threadIdx.x;
  const float4* p = (const float4*)(s + (size_t)idx * 8);
  const float4 a = p[0], bq = p[1];
  uint4 o;
  o.x = pk2(a.x, a.y);   o.y = pk2(a.z, a.w);
  o.z = pk2(bq.x, bq.y); o.w = pk2(bq.z, bq.w);
  *(uint4*)(dst + ((size_t)blockIdx.y << 20) + (size_t)idx * 8) = o;
}

// ---------------------------------------------------------------------------
// Pure-bf16 NT GEMM, m97 structure (gl_lds both sides), 128x128, BK=32.
// Epilogues: 0=QH [B,H,S,DK], 1=KH [B,H,T,DK], 2=VT [B,H,DK,T], 3=RH [H,T,DK],
//            4=fp32 [N,1024]
// ---------------------------------------------------------------------------
template <int EPI>
__global__ __launch_bounds__(256)
void gemm_bf(const u16* __restrict__ X, const u16* __restrict__ W,
             void* __restrict__ O) {
  __shared__ u16 As[128 * 32];
  __shared__ u16 Bs[128 * 32];
  const int tid = threadIdx.x;
  const int lane = tid & 63, wave = tid >> 6;
  const int fr = lane & 15, fq = lane >> 4;
  const int n0 = blockIdx.x * 128, m0 = blockIdx.y * 128;
  const int wr = (wave >> 1) * 64, wc = (wave & 1) * 64;
  f32x4 acc[4][4] = {};

  const int lrow = lane >> 2, lcol = (lane & 3) * 8;
  const u16* xg0 = X + (size_t)(n0 + wave * 16 + lrow) * Dd + lcol;
  const u16* xg1 = X + (size_t)(n0 + 64 + wave * 16 + lrow) * Dd + lcol;
  const u16* wg0 = W + (size_t)(m0 + wave * 16 + lrow) * Dd + lcol;
  const u16* wg1 = W + (size_t)(m0 + 64 + wave * 16 + lrow) * Dd + lcol;
  u16* la0 = &As[(wave * 16) * 32];
  u16* la1 = &As[(64 + wave * 16) * 32];
  u16* lb0 = &Bs[(wave * 16) * 32];
  u16* lb1 = &Bs[(64 + wave * 16) * 32];

  for (int k0 = 0; k0 < Dd; k0 += 32) {
    gl_lds16(xg0 + k0, la0);
    gl_lds16(xg1 + k0, la1);
    gl_lds16(wg0 + k0, lb0);
    gl_lds16(wg1 + k0, lb1);
    __syncthreads();
    s16x8 af[4], bfv[4];
#pragma unroll
    for (int i = 0; i < 4; ++i)
      af[i] = *(const s16x8*)&As[(wr + i * 16 + fr) * 32 + fq * 8];
#pragma unroll
    for (int j = 0; j < 4; ++j)
      bfv[j] = *(const s16x8*)&Bs[(wc + j * 16 + fr) * 32 + fq * 8];
#pragma unroll
    for (int i = 0; i < 4; ++i)
#pragma unroll
      for (int j = 0; j < 4; ++j)
        acc[i][j] = mfma16(af[i], bfv[j], acc[i][j]);
    __syncthreads();
  }

#pragma unroll
  for (int i = 0; i < 4; ++i)
#pragma unroll
    for (int j = 0; j < 4; ++j) {
      if constexpr (EPI == 2) {
        const int grow = n0 + wr + i * 16 + fq * 4;
        const int m = m0 + wc + j * 16 + fr;
        const int bb = grow >> 11, t = grow & 2047;
        const int hh = m >> 6, dk = m & 63;
        ushort4 pk4;
        pk4.x = f2bf(acc[i][j][0]); pk4.y = f2bf(acc[i][j][1]);
        pk4.z = f2bf(acc[i][j][2]); pk4.w = f2bf(acc[i][j][3]);
        *(ushort4*)&((u16*)O)[(((size_t)(bb * Hh + hh) * DKk + dk) << 11) + t] = pk4;
      } else {
#pragma unroll
        for (int r = 0; r < 4; ++r) {
          const int n = n0 + wr + i * 16 + fq * 4 + r;
          const int m = m0 + wc + j * 16 + fr;
          const float y = acc[i][j][r];
          if constexpr (EPI == 0) {
            const int bb = n >> 10, s = n & 1023, hh = m >> 6, dk = m & 63;
            ((u16*)O)[((size_t)(bb * Hh + hh) * Ss + s) * DKk + dk] = f2bf(y);
          } else if constexpr (EPI == 1) {
            const int bb = n >> 11, t = n & 2047, hh = m >> 6, dk = m & 63;
            ((u16*)O)[((size_t)(bb * Hh + hh) * Tt + t) * DKk + dk] = f2bf(y);
          } else if constexpr (EPI == 3) {
            const int hh = m >> 6, dk = m & 63;
            ((u16*)O)[((size_t)hh * Tt + n) * DKk + dk] = f2bf(y);
          } else {
            ((float*)O)[(size_t)n * Dd + m] = y;
          }
        }
      }
    }
}

// ---------------------------------------------------------------------------
// Fused TXL attention v4.
// 256 blocks x 512 threads; block bh-mapped for XCD locality, processes tile
// pair (bx0, 7-bx0) sequentially -> constant 50 chunks/block (perfect balance).
// K and Rh B-fragments: direct coalesced global loads into registers,
// prefetched one chunk ahead (no Ks/RB LDS). V double-buffered in LDS,
// one barrier/chunk. cmax via DPP. Denominator via ones-row MFMA.
// Q bias (u / v_bias) applied in-kernel.
// ---------------------------------------------------------------------------
__global__ __launch_bounds__(512, 2)
void attn4(const u16* __restrict__ QH, const u16* __restrict__ KH,
           const u16* __restrict__ VT, const u16* __restrict__ RH,
           const float* __restrict__ ub, const float* __restrict__ vbb,
           u16* __restrict__ CONCAT) {
  __shared__ u16 Vs[2][64][72];
  __shared__ u16 Vone[16][72];
  __shared__ u16 Pl[8][16][72];

  const int tid = threadIdx.x;
  const int wave = tid >> 6, lane = tid & 63;
  const int fr = lane & 15, fq = lane >> 4;

  const int wid = blockIdx.x;
  const int x = wid & 7, y = wid >> 3;
  const int bh = x * 8 + (y >> 2);   // 4 consecutive-y blocks share (b,h) on one XCD
  const int bx0 = y & 3;
  const int h = bh & 15, b = bh >> 4;

  const u16* qB  = QH + (size_t)bh * Ss * DKk;
  const u16* khB = KH + (size_t)bh * Tt * DKk;
  const u16* vtB = VT + (size_t)bh * DKk * Tt;
  const u16* rhB = RH + (size_t)h * Tt * DKk;

  for (int idx = tid; idx < 16 * 72; idx += 512) {
    const int rr = idx / 72, cc = idx - rr * 72;
    Vone[rr][cc] = (rr == 0 && cc < 64) ? (u16)0x3F80 : (u16)0;
  }

  // head bias, k-dims [fq*8..fq*8+8) and [32+fq*8..)
  float ulo[8], uhi[8], vlo[8], vhi[8];
  {
    const float* up = ub + h * 64 + fq * 8;
    const float* vp = vbb + h * 64 + fq * 8;
    *(float4*)&ulo[0] = *(const float4*)up;
    *(float4*)&ulo[4] = *(const float4*)(up + 4);
    *(float4*)&uhi[0] = *(const float4*)(up + 32);
    *(float4*)&uhi[4] = *(const float4*)(up + 36);
    *(float4*)&vlo[0] = *(const float4*)vp;
    *(float4*)&vlo[4] = *(const float4*)(vp + 4);
    *(float4*)&vhi[0] = *(const float4*)(vp + 32);
    *(float4*)&vhi[4] = *(const float4*)(vp + 36);
  }

  const int krow = tid >> 3, kcol = (tid & 7) * 8;
  const float SC = 0.18033688011f;  // 0.125 * log2(e)

  for (int pass = 0; pass < 2; ++pass) {
    const int bx = pass ? (7 - bx0) : bx0;
    const int i0 = bx * 128;
    const int r0 = i0 + wave * 16;
    const int nch = 2 * bx + 18;
    const int base = (i0 + 1023) & 2047;

    // Q fragments + bias
    const u16* qp = qB + (size_t)(r0 + fr) * DKk + fq * 8;
    const s16x8 q0 = *(const s16x8*)qp;
    const s16x8 q1 = *(const s16x8*)(qp + 32);
    s16x8 qu0, qu1, qv0, qv1;
    {
      union U8 { s16x8 v; uint32_t w[4]; } a0, a1, c0, c1;
#pragma unroll
      for (int e = 0; e < 4; ++e) {
        a0.w[e] = pk2(b2f(q0[2*e]) + ulo[2*e], b2f(q0[2*e+1]) + ulo[2*e+1]);
        a1.w[e] = pk2(b2f(q1[2*e]) + uhi[2*e], b2f(q1[2*e+1]) + uhi[2*e+1]);
        c0.w[e] = pk2(b2f(q0[2*e]) + vlo[2*e], b2f(q0[2*e+1]) + vlo[2*e+1]);
        c1.w[e] = pk2(b2f(q1[2*e]) + vhi[2*e], b2f(q1[2*e+1]) + vhi[2*e+1]);
      }
      qu0 = a0.v; qu1 = a1.v; qv0 = c0.v; qv1 = c1.v;
    }

    // prologue: K/R fragments for chunk 0 (direct global, coalesced); V chunk 0
    s16x8 kf[4][2], rf[5][2];
#pragma unroll
    for (int ct = 0; ct < 4; ++ct)
#pragma unroll
      for (int hh = 0; hh < 2; ++hh)
        kf[ct][hh] = *(const s16x8*)(khB + (size_t)(ct * 16 + fr) * DKk + hh * 32 + fq * 8);
#pragma unroll
    for (int mt = 0; mt < 5; ++mt)
#pragma unroll
      for (int hh = 0; hh < 2; ++hh)
        rf[mt][hh] = *(const s16x8*)(rhB +
            (size_t)((base + wave * 16 + mt * 16 + fr) & 2047) * DKk + hh * 32 + fq * 8);
    uint4 vx = *(const uint4*)(vtB + (size_t)krow * Tt + kcol);

    f32x4 oacc[4] = {};
    f32x4 oacc2 = {};
    float mrun[4];
#pragma unroll
    for (int r = 0; r < 4; ++r) mrun[r] = -1e30f;

    *(uint4*)&Vs[0][krow][kcol] = vx;
    __syncthreads();

    for (int c = 0; c < nch; ++c) {
      const int cur = c & 1, j0 = c * 64;
      const bool more = (c + 1 < nch);
      if (more) vx = *(const uint4*)(vtB + (size_t)krow * Tt + (j0 + 64) + kcol);

      // G strip from register R-frags
      f32x4 g[5];
      __builtin_amdgcn_s_setprio(1);
#pragma unroll
      for (int mt = 0; mt < 5; ++mt) {
        f32x4 t = {};
        t = mfma16(qv0, rf[mt][0], t);
        t = mfma16(qv1, rf[mt][1], t);
        g[mt] = t;
      }
      __builtin_amdgcn_s_setprio(0);
      // advance R frags (positions shift by 64 = 4 tiles)
      rf[0][0] = rf[4][0]; rf[0][1] = rf[4][1];
      if (more) {
#pragma unroll
        for (int mt = 1; mt < 5; ++mt)
#pragma unroll
          for (int hh = 0; hh < 2; ++hh)
            rf[mt][hh] = *(const s16x8*)(rhB +
                (size_t)((base + j0 + 64 + wave * 16 + mt * 16 + fr) & 2047) * DKk +
                hh * 32 + fq * 8);
      }

      // BD diagonal gather
      f32x4 pacc[4];
#pragma unroll
      for (int r = 0; r < 4; ++r) {
        const int s = fq * 4 + r + fr;
        const int src = fq * 16 + (s & 15);
        const bool carry = s >= 16;
        const float s0 = __shfl(g[0][r], src);
        const float s1 = __shfl(g[1][r], src);
        const float s2 = __shfl(g[2][r], src);
        const float s3 = __shfl(g[3][r], src);
        const float s4 = __shfl(g[4][r], src);
        pacc[0][r] = carry ? s1 : s0;
        pacc[1][r] = carry ? s2 : s1;
        pacc[2][r] = carry ? s3 : s2;
        pacc[3][r] = carry ? s4 : s3;
      }

      // AC accumulate from register K-frags
      __builtin_amdgcn_s_setprio(1);
#pragma unroll
      for (int ct = 0; ct < 4; ++ct) {
        pacc[ct] = mfma16(qu0, kf[ct][0], pacc[ct]);
        pacc[ct] = mfma16(qu1, kf[ct][1], pacc[ct]);
      }
      __builtin_amdgcn_s_setprio(0);
      if (more) {
#pragma unroll
        for (int ct = 0; ct < 4; ++ct)
#pragma unroll
          for (int hh = 0; hh < 2; ++hh)
            kf[ct][hh] = *(const s16x8*)(khB +
                (size_t)(j0 + 64 + ct * 16 + fr) * DKk + hh * 32 + fq * 8);
      }

      // scale to log2 domain + mask
      if (j0 + 63 > r0 + MEMm) {
#pragma unroll
        for (int ct = 0; ct < 4; ++ct)
#pragma unroll
          for (int r = 0; r < 4; ++r) {
            const int gi = r0 + fq * 4 + r, gj = j0 + ct * 16 + fr;
            const float vv = pacc[ct][r] * SC;
            pacc[ct][r] = (gj > gi + MEMm) ? -1e30f : vv;
          }
      } else {
#pragma unroll
        for (int ct = 0; ct < 4; ++ct)
#pragma unroll
          for (int r = 0; r < 4; ++r) pacc[ct][r] *= SC;
      }

      // online softmax: row max via DPP (no DS)
      float alpha[4];
#pragma unroll
      for (int r = 0; r < 4; ++r) {
        float cm = fmaxf(fmaxf(pacc[0][r], pacc[1][r]), fmaxf(pacc[2][r], pacc[3][r]));
        cm = rowmax16(cm);
        const float mn = fmaxf(mrun[r], cm);
        alpha[r] = exp2f(mrun[r] - mn);
        mrun[r] = mn;
      }
#pragma unroll
      for (int ct = 0; ct < 4; ++ct)
#pragma unroll
        for (int r = 0; r < 4; ++r)
          pacc[ct][r] = exp2f(pacc[ct][r] - mrun[r]);
#pragma unroll
      for (int t = 0; t < 4; ++t)
#pragma unroll
        for (int r = 0; r < 4; ++r) oacc[t][r] *= alpha[r];
#pragma unroll
      for (int r = 0; r < 4; ++r) oacc2[r] *= alpha[r];

      // P -> LDS -> A-fragments; PV (+ denominator via ones row)
#pragma unroll
      for (int ct = 0; ct < 4; ++ct)
#pragma unroll
        for (int r = 0; r < 4; ++r)
          Pl[wave][fq * 4 + r][ct * 16 + fr] = f2bf(pacc[ct][r]);
      asm volatile("s_waitcnt lgkmcnt(0)" ::: "memory");
      __builtin_amdgcn_sched_barrier(0);
      const s16x8 ap0 = *(const s16x8*)&Pl[wave][fr][fq * 8];
      const s16x8 ap1 = *(const s16x8*)&Pl[wave][fr][32 + fq * 8];
      __builtin_amdgcn_s_setprio(1);
#pragma unroll
      for (int t = 0; t < 4; ++t) {
        oacc[t] = mfma16(ap0, *(const s16x8*)&Vs[cur][t * 16 + fr][fq * 8], oacc[t]);
        oacc[t] = mfma16(ap1, *(const s16x8*)&Vs[cur][t * 16 + fr][32 + fq * 8], oacc[t]);
      }
      oacc2 = mfma16(ap0, *(const s16x8*)&Vone[fr][fq * 8], oacc2);
      oacc2 = mfma16(ap1, *(const s16x8*)&Vone[fr][32 + fq * 8], oacc2);
      __builtin_amdgcn_s_setprio(0);

      if (more) *(uint4*)&Vs[cur ^ 1][krow][kcol] = vx;
      __syncthreads();
    }

    // epilogue
    float linv[4];
#pragma unroll
    for (int r = 0; r < 4; ++r)
      linv[r] = 1.0f / __shfl(oacc2[r], lane & 48);
#pragma unroll
    for (int t = 0; t < 4; ++t)
#pragma unroll
      for (int r = 0; r < 4; ++r) {
        const int gi = r0 + fq * 4 + r;
        CONCAT[((size_t)b * Ss + gi) * Dd + h * DKk + t * 16 + fr] =
            f2bf(oacc[t][r] * linv[r]);
      }
  }
}

// ---------------------------------------------------------------------------
extern "C" void kernel_launch(void* const* d_in, const int* in_sizes, int n_in,
                              void* d_out, int out_size, void* d_ws,
                              size_t ws_size, hipStream_t stream) {
  (void)in_sizes; (void)n_in; (void)out_size; (void)ws_size;
  const float* q  = (const float*)d_in[0];
  const float* k  = (const float*)d_in[1];
  const float* v  = (const float*)d_in[2];
  // d_in[3] = mask: analytic (j <= i + MEM), unused
  const float* u  = (const float*)d_in[4];
  const float* vb = (const float*)d_in[5];
  const float* Wq = (const float*)d_in[6];
  const float* Wk = (const float*)d_in[7];
  const float* Wv = (const float*)d_in[8];
  const float* Wr = (const float*)d_in[9];
  const float* Wo = (const float*)d_in[10];
  const float* R  = (const float*)d_in[11];

  char* ws = (char*)d_ws;
  u16* QH  = (u16*)ws; ws += 8388608;    // [B,H,S,DK] bf16
  u16* KH  = (u16*)ws; ws += 16777216;   // [B,H,T,DK]
  u16* VT  = (u16*)ws; ws += 16777216;   // [B,H,DK,T]
  u16* RH  = (u16*)ws; ws += 4194304;    // [H,T,DK]
  u16* Wb  = (u16*)ws; ws += 10485760;   // 5 x 1M bf16 weights
  u16* STG = (u16*)ws;                   // 16 MB activation staging / CONCAT

  cvt5<<<dim3(512, 5), 256, 0, stream>>>(Wq, Wk, Wv, Wr, Wo, Wb);
  const size_t M1 = (size_t)1 << 20;

  cvt_f32_bf16<<<2048, 256, 0, stream>>>(q, STG, 524288);
  gemm_bf<0><<<dim3(32, 8), 256, 0, stream>>>(STG, Wb, QH);
  cvt_f32_bf16<<<2048, 256, 0, stream>>>(k, STG, 1048576);
  gemm_bf<1><<<dim3(64, 8), 256, 0, stream>>>(STG, Wb + M1, KH);
  cvt_f32_bf16<<<2048, 256, 0, stream>>>(v, STG, 1048576);
  gemm_bf<2><<<dim3(64, 8), 256, 0, stream>>>(STG, Wb + 2 * M1, VT);
  cvt_f32_bf16<<<1024, 256, 0, stream>>>(R, STG, 262144);
  gemm_bf<3><<<dim3(16, 8), 256, 0, stream>>>(STG, Wb + 3 * M1, RH);

  attn4<<<256, 512, 0, stream>>>(QH, KH, VT, RH, u, vb, STG);
  gemm_bf<4><<<dim3(32, 8), 256, 0, stream>>>(STG, Wb + 4 * M1, (float*)d_out);
}

// Round 7
// 264.313 us; speedup vs baseline: 1.2775x; 1.2775x over previous
//
#include <hip/hip_runtime.h>
#include <hip/hip_bf16.h>
#include <stdint.h>

#define Ss   1024
#define MEMm 1024
#define Tt   2048
#define Dd   1024
#define Hh   16
#define DKk  64

typedef unsigned short u16;
using f32x4 = __attribute__((ext_vector_type(4))) float;
using s16x8 = __attribute__((ext_vector_type(8))) short;

__device__ __forceinline__ u16 f2bf(float x) {
  __hip_bfloat16 h = __float2bfloat16(x);
  return *(reinterpret_cast<u16*>(&h));
}
__device__ __forceinline__ float b2f(short s) {
  union { uint32_t u; float f; } c; c.u = ((uint32_t)(u16)s) << 16; return c.f;
}
__device__ __forceinline__ uint32_t pk2(float lo, float hi) {
  return (uint32_t)f2bf(lo) | ((uint32_t)f2bf(hi) << 16);
}
__device__ __forceinline__ f32x4 mfma16(s16x8 a, s16x8 b, f32x4 c) {
  return __builtin_amdgcn_mfma_f32_16x16x32_bf16(a, b, c, 0, 0, 0);
}
__device__ __forceinline__ void gl_lds16(const u16* g, u16* l) {
  __builtin_amdgcn_global_load_lds(
      (const __attribute__((address_space(1))) uint32_t*)g,
      (__attribute__((address_space(3))) uint32_t*)l, 16, 0, 0);
}
// 16-lane (fr-group) max via DPP butterfly: xor masks {1,2,7,15}
__device__ __forceinline__ float rowmax16(float x) {
  int v = __builtin_bit_cast(int, x);
  int t = __builtin_amdgcn_update_dpp(v, v, 0xB1, 0xF, 0xF, true);
  x = fmaxf(x, __builtin_bit_cast(float, t)); v = __builtin_bit_cast(int, x);
  t = __builtin_amdgcn_update_dpp(v, v, 0x4E, 0xF, 0xF, true);
  x = fmaxf(x, __builtin_bit_cast(float, t)); v = __builtin_bit_cast(int, x);
  t = __builtin_amdgcn_update_dpp(v, v, 0x141, 0xF, 0xF, true);
  x = fmaxf(x, __builtin_bit_cast(float, t)); v = __builtin_bit_cast(int, x);
  t = __builtin_amdgcn_update_dpp(v, v, 0x140, 0xF, 0xF, true);
  x = fmaxf(x, __builtin_bit_cast(float, t));
  return x;
}

// ---------------------------------------------------------------------------
// fp32 -> bf16 converts
// ---------------------------------------------------------------------------
__global__ __launch_bounds__(256)
void cvt_f32_bf16(const float* __restrict__ in, u16* __restrict__ out, int n8) {
  int i = blockIdx.x * 256 + threadIdx.x;
  const int stride = gridDim.x * 256;
  for (; i < n8; i += stride) {
    const float4* p = (const float4*)(in + (size_t)i * 8);
    const float4 a = p[0], bq = p[1];
    uint4 o;
    o.x = pk2(a.x, a.y);   o.y = pk2(a.z, a.w);
    o.z = pk2(bq.x, bq.y); o.w = pk2(bq.z, bq.w);
    *(uint4*)(out + (size_t)i * 8) = o;
  }
}
__global__ __launch_bounds__(256)
void cvt5(const float* __restrict__ w0, const float* __restrict__ w1,
          const float* __restrict__ w2, const float* __restrict__ w3,
          const float* __restrict__ w4, u16* __restrict__ dst) {
  const float* s;
  switch (blockIdx.y) {
    case 0: s = w0; break; case 1: s = w1; break; case 2: s = w2; break;
    case 3: s = w3; break; default: s = w4; break;
  }
  const int idx = blockIdx.x * 256 + threadIdx.x;
  const float4* p = (const float4*)(s + (size_t)idx * 8);
  const float4 a = p[0], bq = p[1];
  uint4 o;
  o.x = pk2(a.x, a.y);   o.y = pk2(a.z, a.w);
  o.z = pk2(bq.x, bq.y); o.w = pk2(bq.z, bq.w);
  *(uint4*)(dst + ((size_t)blockIdx.y << 20) + (size_t)idx * 8) = o;
}

// ---------------------------------------------------------------------------
// Pure-bf16 NT GEMM, m97 structure (gl_lds both sides), 128x128, BK=32.
// ---------------------------------------------------------------------------
template <int EPI>
__global__ __launch_bounds__(256)
void gemm_bf(const u16* __restrict__ X, const u16* __restrict__ W,
             void* __restrict__ O) {
  __shared__ u16 As[128 * 32];
  __shared__ u16 Bs[128 * 32];
  const int tid = threadIdx.x;
  const int lane = tid & 63, wave = tid >> 6;
  const int fr = lane & 15, fq = lane >> 4;
  const int n0 = blockIdx.x * 128, m0 = blockIdx.y * 128;
  const int wr = (wave >> 1) * 64, wc = (wave & 1) * 64;
  f32x4 acc[4][4] = {};

  const int lrow = lane >> 2, lcol = (lane & 3) * 8;
  const u16* xg0 = X + (size_t)(n0 + wave * 16 + lrow) * Dd + lcol;
  const u16* xg1 = X + (size_t)(n0 + 64 + wave * 16 + lrow) * Dd + lcol;
  const u16* wg0 = W + (size_t)(m0 + wave * 16 + lrow) * Dd + lcol;
  const u16* wg1 = W + (size_t)(m0 + 64 + wave * 16 + lrow) * Dd + lcol;
  u16* la0 = &As[(wave * 16) * 32];
  u16* la1 = &As[(64 + wave * 16) * 32];
  u16* lb0 = &Bs[(wave * 16) * 32];
  u16* lb1 = &Bs[(64 + wave * 16) * 32];

  for (int k0 = 0; k0 < Dd; k0 += 32) {
    gl_lds16(xg0 + k0, la0);
    gl_lds16(xg1 + k0, la1);
    gl_lds16(wg0 + k0, lb0);
    gl_lds16(wg1 + k0, lb1);
    __syncthreads();
    s16x8 af[4], bfv[4];
#pragma unroll
    for (int i = 0; i < 4; ++i)
      af[i] = *(const s16x8*)&As[(wr + i * 16 + fr) * 32 + fq * 8];
#pragma unroll
    for (int j = 0; j < 4; ++j)
      bfv[j] = *(const s16x8*)&Bs[(wc + j * 16 + fr) * 32 + fq * 8];
#pragma unroll
    for (int i = 0; i < 4; ++i)
#pragma unroll
      for (int j = 0; j < 4; ++j)
        acc[i][j] = mfma16(af[i], bfv[j], acc[i][j]);
    __syncthreads();
  }

#pragma unroll
  for (int i = 0; i < 4; ++i)
#pragma unroll
    for (int j = 0; j < 4; ++j) {
      if constexpr (EPI == 2) {
        const int grow = n0 + wr + i * 16 + fq * 4;
        const int m = m0 + wc + j * 16 + fr;
        const int bb = grow >> 11, t = grow & 2047;
        const int hh = m >> 6, dk = m & 63;
        ushort4 pk4;
        pk4.x = f2bf(acc[i][j][0]); pk4.y = f2bf(acc[i][j][1]);
        pk4.z = f2bf(acc[i][j][2]); pk4.w = f2bf(acc[i][j][3]);
        *(ushort4*)&((u16*)O)[(((size_t)(bb * Hh + hh) * DKk + dk) << 11) + t] = pk4;
      } else {
#pragma unroll
        for (int r = 0; r < 4; ++r) {
          const int n = n0 + wr + i * 16 + fq * 4 + r;
          const int m = m0 + wc + j * 16 + fr;
          const float y = acc[i][j][r];
          if constexpr (EPI == 0) {
            const int bb = n >> 10, s = n & 1023, hh = m >> 6, dk = m & 63;
            ((u16*)O)[((size_t)(bb * Hh + hh) * Ss + s) * DKk + dk] = f2bf(y);
          } else if constexpr (EPI == 1) {
            const int bb = n >> 11, t = n & 2047, hh = m >> 6, dk = m & 63;
            ((u16*)O)[((size_t)(bb * Hh + hh) * Tt + t) * DKk + dk] = f2bf(y);
          } else if constexpr (EPI == 3) {
            const int hh = m >> 6, dk = m & 63;
            ((u16*)O)[((size_t)hh * Tt + n) * DKk + dk] = f2bf(y);
          } else {
            ((float*)O)[(size_t)n * Dd + m] = y;
          }
        }
      }
    }
}

// ---------------------------------------------------------------------------
// Fused TXL attention v7: like v6 (4 waves x 32 rows, XOR-swizzled 64-u16 LDS
// rows, RB ring, DPP rowmax, register ones-frag denominator, log2 softmax)
// but staging is REG-STAGED ds_write_b128 (rounds 2-3 proven mechanism):
// global->uint4 regs issued at top of chunk (latency hides under compute),
// per-lane swizzled ds_write after the bottom barrier. No global_load_lds.
// ---------------------------------------------------------------------------
__global__ __launch_bounds__(256, 2)
void attn7(const u16* __restrict__ QH, const u16* __restrict__ KH,
           const u16* __restrict__ VT, const u16* __restrict__ RH,
           const float* __restrict__ ub, const float* __restrict__ vbb,
           u16* __restrict__ CONCAT) {
  __shared__ u16 Ks[64 * 64];
  __shared__ u16 Vt[64 * 64];
  __shared__ u16 RB[256 * 64];
  __shared__ u16 Pl[4][2][16 * 72];

  const int tid = threadIdx.x;
  const int wave = tid >> 6, lane = tid & 63;
  const int fr = lane & 15, fq = lane >> 4;

  const int wid = blockIdx.x;
  const int bx = (wid < 256) ? (wid >> 6) : (11 - (wid >> 6));
  const int bh = wid & 63;
  const int h = bh & 15, b = bh >> 4;
  const int i0 = bx * 128;
  const int r0 = i0 + wave * 32;
  const int nch = 2 * bx + 18;
  const int base = (i0 + 1023) & 2047;

  const u16* qB  = QH + (size_t)bh * (Ss * DKk);
  const u16* khB = KH + (size_t)bh * (Tt * DKk);
  const u16* vtB = VT + (size_t)bh * (DKk * Tt);
  const u16* rhB = RH + (size_t)h * (Tt * DKk);

  // head biases for this lane's k-slots
  float ulo[8], uhi[8], vlo[8], vhi[8];
  {
    const float* up = ub + h * 64 + fq * 8;
    const float* vp = vbb + h * 64 + fq * 8;
    *(float4*)&ulo[0] = *(const float4*)up;
    *(float4*)&ulo[4] = *(const float4*)(up + 4);
    *(float4*)&uhi[0] = *(const float4*)(up + 32);
    *(float4*)&uhi[4] = *(const float4*)(up + 36);
    *(float4*)&vlo[0] = *(const float4*)vp;
    *(float4*)&vlo[4] = *(const float4*)(vp + 4);
    *(float4*)&vhi[0] = *(const float4*)(vp + 32);
    *(float4*)&vhi[4] = *(const float4*)(vp + 36);
  }

  // Q fragments + bias, two row-sets
  s16x8 qu[2][2], qv[2][2];
#pragma unroll
  for (int s = 0; s < 2; ++s) {
    const u16* qp = qB + (size_t)(r0 + s * 16 + fr) * DKk + fq * 8;
    const s16x8 q0 = *(const s16x8*)qp;
    const s16x8 q1 = *(const s16x8*)(qp + 32);
    union U8 { s16x8 v; uint32_t w[4]; } a0, a1, c0, c1;
#pragma unroll
    for (int e = 0; e < 4; ++e) {
      a0.w[e] = pk2(b2f(q0[2*e]) + ulo[2*e], b2f(q0[2*e+1]) + ulo[2*e+1]);
      a1.w[e] = pk2(b2f(q1[2*e]) + uhi[2*e], b2f(q1[2*e+1]) + uhi[2*e+1]);
      c0.w[e] = pk2(b2f(q0[2*e]) + vlo[2*e], b2f(q0[2*e+1]) + vlo[2*e+1]);
      c1.w[e] = pk2(b2f(q1[2*e]) + vhi[2*e], b2f(q1[2*e+1]) + vhi[2*e+1]);
    }
    qu[s][0] = a0.v; qu[s][1] = a1.v; qv[s][0] = c0.v; qv[s][1] = c1.v;
  }

  // ones B-fragment (output col 0) for the denominator MFMA
  s16x8 vone;
  {
    union U8 { s16x8 v; uint32_t w[4]; } o;
    const uint32_t f = (fr == 0) ? 0x3F803F80u : 0u;
#pragma unroll
    for (int e = 0; e < 4; ++e) o.w[e] = f;
    vone = o.v;
  }

  // staging ownership: rows {row0,row1}, chunk sch; swizzle chunk = sch^srow
  const int srow = lane >> 3, sch = lane & 7;
  const int row0 = wave * 8 + srow;        // &7 == srow
  const int row1 = wave * 8 + 32 + srow;   // &7 == srow
  const int swc = (sch ^ srow) * 8;        // swizzled global chunk offset

  // prologue: RB ring rows [0,192), K/V chunk 0 (reg-staged, plain ds_write)
#pragma unroll
  for (int p = 0; p < 6; ++p) {
    const int off = p * 32 + wave * 8 + srow;  // off&7 == srow
    const uint4 rr =
        *(const uint4*)(rhB + (size_t)((base + off) & 2047) * 64 + swc);
    *(uint4*)&RB[off * 64 + sch * 8] = rr;
  }
  {
    const uint4 k0 = *(const uint4*)(khB + (size_t)row0 * 64 + swc);
    const uint4 k1 = *(const uint4*)(khB + (size_t)row1 * 64 + swc);
    const uint4 v0 = *(const uint4*)(vtB + (size_t)row0 * Tt + swc);
    const uint4 v1 = *(const uint4*)(vtB + (size_t)row1 * Tt + swc);
    *(uint4*)&Ks[row0 * 64 + sch * 8] = k0;
    *(uint4*)&Ks[row1 * 64 + sch * 8] = k1;
    *(uint4*)&Vt[row0 * 64 + sch * 8] = v0;
    *(uint4*)&Vt[row1 * 64 + sch * 8] = v1;
  }

  f32x4 oacc[2][4] = {};
  f32x4 oacc2[2] = {};
  float mrun[2][4];
#pragma unroll
  for (int s = 0; s < 2; ++s)
#pragma unroll
    for (int r = 0; r < 4; ++r) mrun[s][r] = -1e30f;

  const float SC = 0.18033688011f;  // 0.125 * log2(e)

  for (int c = 0; c < nch; ++c) {
    const int j0 = c * 64;
    const bool more = (c + 1 < nch);
    __syncthreads();  // staged ds_writes visible

    // issue next-chunk global loads (latency hides under this chunk's compute)
    uint4 kr0, kr1, vr0, vr1;
    if (more) {
      kr0 = *(const uint4*)(khB + (size_t)(j0 + 64 + row0) * 64 + swc);
      kr1 = *(const uint4*)(khB + (size_t)(j0 + 64 + row1) * 64 + swc);
      vr0 = *(const uint4*)(vtB + (size_t)row0 * Tt + (j0 + 64) + swc);
      vr1 = *(const uint4*)(vtB + (size_t)row1 * Tt + (j0 + 64) + swc);
    }
    const int offA0 = j0 + 192 + wave * 8 + srow;  // &7 == srow
    const int offA1 = offA0 + 32;
    const uint4 rr0 =
        *(const uint4*)(rhB + (size_t)((base + offA0) & 2047) * 64 + swc);
    const uint4 rr1 =
        *(const uint4*)(rhB + (size_t)((base + offA1) & 2047) * 64 + swc);

    // R fragments (shared window tiles 0..5)
    s16x8 rf[6][2];
#pragma unroll
    for (int mt = 0; mt < 6; ++mt) {
      const int rho = (j0 + wave * 32 + mt * 16 + fr) & 255;
#pragma unroll
      for (int hh = 0; hh < 2; ++hh)
        rf[mt][hh] = *(const s16x8*)&RB[rho * 64 + (((hh * 4 + fq) ^ (rho & 7)) * 8)];
    }

    // G strips: set s uses tiles s..s+4
    f32x4 g[2][5];
    __builtin_amdgcn_s_setprio(1);
#pragma unroll
    for (int s = 0; s < 2; ++s)
#pragma unroll
      for (int k = 0; k < 5; ++k) {
        f32x4 t = {};
        t = mfma16(qv[s][0], rf[s + k][0], t);
        t = mfma16(qv[s][1], rf[s + k][1], t);
        g[s][k] = t;
      }
    __builtin_amdgcn_s_setprio(0);

    // K fragments (shared between row-sets)
    s16x8 kf[4][2];
#pragma unroll
    for (int ct = 0; ct < 4; ++ct) {
      const int row = ct * 16 + fr;
#pragma unroll
      for (int hh = 0; hh < 2; ++hh)
        kf[ct][hh] = *(const s16x8*)&Ks[row * 64 + (((hh * 4 + fq) ^ (row & 7)) * 8)];
    }

    // diag gather + AC accumulate
    f32x4 pacc[2][4];
#pragma unroll
    for (int s = 0; s < 2; ++s) {
#pragma unroll
      for (int r = 0; r < 4; ++r) {
        const int sum = fq * 4 + r + fr;
        const int src = fq * 16 + (sum & 15);
        const bool cy = sum >= 16;
        const float s0 = __shfl(g[s][0][r], src);
        const float s1 = __shfl(g[s][1][r], src);
        const float s2 = __shfl(g[s][2][r], src);
        const float s3 = __shfl(g[s][3][r], src);
        const float s4 = __shfl(g[s][4][r], src);
        pacc[s][0][r] = cy ? s1 : s0;
        pacc[s][1][r] = cy ? s2 : s1;
        pacc[s][2][r] = cy ? s3 : s2;
        pacc[s][3][r] = cy ? s4 : s3;
      }
    }
    __builtin_amdgcn_s_setprio(1);
#pragma unroll
    for (int s = 0; s < 2; ++s)
#pragma unroll
      for (int ct = 0; ct < 4; ++ct) {
        pacc[s][ct] = mfma16(qu[s][0], kf[ct][0], pacc[s][ct]);
        pacc[s][ct] = mfma16(qu[s][1], kf[ct][1], pacc[s][ct]);
      }
    __builtin_amdgcn_s_setprio(0);

    // scale (log2 domain) + mask, online softmax, rescale
#pragma unroll
    for (int s = 0; s < 2; ++s) {
      const int rbase = r0 + s * 16;
      if (j0 + 63 > rbase + MEMm) {
#pragma unroll
        for (int ct = 0; ct < 4; ++ct)
#pragma unroll
          for (int r = 0; r < 4; ++r) {
            const int gi = rbase + fq * 4 + r, gj = j0 + ct * 16 + fr;
            const float vv = pacc[s][ct][r] * SC;
            pacc[s][ct][r] = (gj > gi + MEMm) ? -1e30f : vv;
          }
      } else {
#pragma unroll
        for (int ct = 0; ct < 4; ++ct)
#pragma unroll
          for (int r = 0; r < 4; ++r) pacc[s][ct][r] *= SC;
      }
      float alpha[4];
#pragma unroll
      for (int r = 0; r < 4; ++r) {
        float cm = fmaxf(fmaxf(pacc[s][0][r], pacc[s][1][r]),
                         fmaxf(pacc[s][2][r], pacc[s][3][r]));
        cm = rowmax16(cm);
        const float mn = fmaxf(mrun[s][r], cm);
        alpha[r] = exp2f(mrun[s][r] - mn);
        mrun[s][r] = mn;
      }
#pragma unroll
      for (int ct = 0; ct < 4; ++ct)
#pragma unroll
        for (int r = 0; r < 4; ++r)
          pacc[s][ct][r] = exp2f(pacc[s][ct][r] - mrun[s][r]);
#pragma unroll
      for (int t = 0; t < 4; ++t)
#pragma unroll
        for (int r = 0; r < 4; ++r) oacc[s][t][r] *= alpha[r];
#pragma unroll
      for (int r = 0; r < 4; ++r) oacc2[s][r] *= alpha[r];
    }

    // P -> LDS (bf16) both sets, then A-fragments
#pragma unroll
    for (int s = 0; s < 2; ++s)
#pragma unroll
      for (int ct = 0; ct < 4; ++ct)
#pragma unroll
        for (int r = 0; r < 4; ++r)
          Pl[wave][s][(fq * 4 + r) * 72 + ct * 16 + fr] = f2bf(pacc[s][ct][r]);
    asm volatile("s_waitcnt lgkmcnt(0)" ::: "memory");
    __builtin_amdgcn_sched_barrier(0);
    s16x8 ap[2][2];
#pragma unroll
    for (int s = 0; s < 2; ++s)
#pragma unroll
      for (int hh = 0; hh < 2; ++hh)
        ap[s][hh] = *(const s16x8*)&Pl[wave][s][fr * 72 + hh * 32 + fq * 8];

    // V fragments (shared) + PV + denominator
    s16x8 vf[4][2];
#pragma unroll
    for (int nt = 0; nt < 4; ++nt) {
      const int row = nt * 16 + fr;
#pragma unroll
      for (int hh = 0; hh < 2; ++hh)
        vf[nt][hh] = *(const s16x8*)&Vt[row * 64 + (((hh * 4 + fq) ^ (row & 7)) * 8)];
    }
    __builtin_amdgcn_s_setprio(1);
#pragma unroll
    for (int s = 0; s < 2; ++s) {
#pragma unroll
      for (int nt = 0; nt < 4; ++nt) {
        oacc[s][nt] = mfma16(ap[s][0], vf[nt][0], oacc[s][nt]);
        oacc[s][nt] = mfma16(ap[s][1], vf[nt][1], oacc[s][nt]);
      }
      oacc2[s] = mfma16(ap[s][0], vone, oacc2[s]);
      oacc2[s] = mfma16(ap[s][1], vone, oacc2[s]);
    }
    __builtin_amdgcn_s_setprio(0);

    __syncthreads();  // all reads of Ks/Vt/RB done
    if (more) {
      *(uint4*)&Ks[row0 * 64 + sch * 8] = kr0;
      *(uint4*)&Ks[row1 * 64 + sch * 8] = kr1;
      *(uint4*)&Vt[row0 * 64 + sch * 8] = vr0;
      *(uint4*)&Vt[row1 * 64 + sch * 8] = vr1;
    }
    *(uint4*)&RB[(offA0 & 255) * 64 + sch * 8] = rr0;
    *(uint4*)&RB[(offA1 & 255) * 64 + sch * 8] = rr1;
  }

  // epilogue
#pragma unroll
  for (int s = 0; s < 2; ++s) {
    float linv[4];
#pragma unroll
    for (int r = 0; r < 4; ++r)
      linv[r] = 1.0f / __shfl(oacc2[s][r], lane & 48);
#pragma unroll
    for (int nt = 0; nt < 4; ++nt)
#pragma unroll
      for (int r = 0; r < 4; ++r) {
        const int gi = r0 + s * 16 + fq * 4 + r;
        CONCAT[((size_t)b * Ss + gi) * Dd + h * DKk + nt * 16 + fr] =
            f2bf(oacc[s][nt][r] * linv[r]);
      }
  }
}

// ---------------------------------------------------------------------------
extern "C" void kernel_launch(void* const* d_in, const int* in_sizes, int n_in,
                              void* d_out, int out_size, void* d_ws,
                              size_t ws_size, hipStream_t stream) {
  (void)in_sizes; (void)n_in; (void)out_size; (void)ws_size;
  const float* q  = (const float*)d_in[0];
  const float* k  = (const float*)d_in[1];
  const float* v  = (const float*)d_in[2];
  // d_in[3] = mask: analytic (j <= i + MEM), unused
  const float* u  = (const float*)d_in[4];
  const float* vb = (const float*)d_in[5];
  const float* Wq = (const float*)d_in[6];
  const float* Wk = (const float*)d_in[7];
  const float* Wv = (const float*)d_in[8];
  const float* Wr = (const float*)d_in[9];
  const float* Wo = (const float*)d_in[10];
  const float* R  = (const float*)d_in[11];

  char* ws = (char*)d_ws;
  u16* QH  = (u16*)ws; ws += 8388608;    // [B,H,S,DK] bf16
  u16* KH  = (u16*)ws; ws += 16777216;   // [B,H,T,DK]
  u16* VT  = (u16*)ws; ws += 16777216;   // [B,H,DK,T]
  u16* RH  = (u16*)ws; ws += 4194304;    // [H,T,DK]
  u16* Wb  = (u16*)ws; ws += 10485760;   // 5 x 1M bf16 weights
  u16* STG = (u16*)ws;                   // 16 MB activation staging / CONCAT

  cvt5<<<dim3(512, 5), 256, 0, stream>>>(Wq, Wk, Wv, Wr, Wo, Wb);
  const size_t M1 = (size_t)1 << 20;

  cvt_f32_bf16<<<2048, 256, 0, stream>>>(q, STG, 524288);
  gemm_bf<0><<<dim3(32, 8), 256, 0, stream>>>(STG, Wb, QH);
  cvt_f32_bf16<<<2048, 256, 0, stream>>>(k, STG, 1048576);
  gemm_bf<1><<<dim3(64, 8), 256, 0, stream>>>(STG, Wb + M1, KH);
  cvt_f32_bf16<<<2048, 256, 0, stream>>>(v, STG, 1048576);
  gemm_bf<2><<<dim3(64, 8), 256, 0, stream>>>(STG, Wb + 2 * M1, VT);
  cvt_f32_bf16<<<1024, 256, 0, stream>>>(R, STG, 262144);
  gemm_bf<3><<<dim3(16, 8), 256, 0, stream>>>(STG, Wb + 3 * M1, RH);

  attn7<<<512, 256, 0, stream>>>(QH, KH, VT, RH, u, vb, STG);
  gemm_bf<4><<<dim3(32, 8), 256, 0, stream>>>(STG, Wb + 4 * M1, (float*)d_out);
}